// Round 5
// baseline (198.662 us; speedup 1.0000x reference)
//
#include <hip/hip_runtime.h>

#define EPS 1e-5f

// ===========================================================================
// Fused encoder: one kernel does gemm1(K=1024)+LN+relu, geo-MLP+LN+relu,
// gemm2(K=384)+LN, and the wc1 projection. Block = 8 rows, grid 256 (1/CU).
// gemm1 is K-split across the 4 waves (L1-balanced: 32 FMAs per 16B/lane of
// weight traffic); partials reduced in LDS (psum overlays the dead x-slab).
// gemm2/proj are wave-per-2-rows over LDS-resident activations.
// Attention branch of the reference is dead code (attn_out unused) — skipped.
// ws: aa @ 0 (4*256*128), cc @ 131072 (4*256*128).
// ===========================================================================
__global__ __launch_bounds__(256) void k_encode(
    const float* __restrict__ tracks, const float* __restrict__ dets,
    const float* __restrict__ wa1, const float* __restrict__ ba1,
    const float* __restrict__ gla, const float* __restrict__ bla,
    const float* __restrict__ wa2, const float* __restrict__ ba2,
    const float* __restrict__ wg1, const float* __restrict__ bg1,
    const float* __restrict__ glg, const float* __restrict__ blg,
    const float* __restrict__ wg2, const float* __restrict__ bg2,
    const float* __restrict__ gf,  const float* __restrict__ bf,
    const float* __restrict__ wc1,
    float* __restrict__ aout, float* __restrict__ cout)
{
    __shared__ float xs[8192];          // [k][r] 32KB; overlaid by psum[w][row][c]
    __shared__ float h1s[256 * 9];      // [c][row], pad 9
    __shared__ float grl[128 * 9];      // [j][row], pad 9
    __shared__ float emb[256 * 9];      // [c][row], pad 9
    __shared__ float red[4][8][2];
    __shared__ float geo_s[8][4];

    const int blk = blockIdx.x;          // 256 blocks: 2048 rows / 8
    const int g0 = blk * 8;
    const int side = g0 >> 10, b = (g0 >> 8) & 3, n0 = g0 & 255;
    const float* xb = (side ? dets : tracks) + (size_t)b * (1028 * 256);
    const int tid = threadIdx.x, w = tid >> 6, lane = tid & 63;
    const int c0 = lane * 4;             // gemm lane -> 4 output cols
    const int r0 = w * 2, r1 = r0 + 1;   // gemm2/proj rows for this wave

    // ---- stage x slab [1024][8] + geo [8][4] ----
    for (int idx = tid; idx < 8192; idx += 256) {
        int k = idx >> 3, r = idx & 7;
        xs[idx] = xb[(size_t)k * 256 + n0 + r];
    }
    if (tid < 32)
        geo_s[tid >> 2][tid & 3] =
            xb[(size_t)(1024 + (tid & 3)) * 256 + n0 + (tid >> 2)];
    __syncthreads();

    // ---- gemm1, K-split: wave w -> k in [w*256, w*256+256) ----
    float acc[8][4];
#pragma unroll
    for (int i = 0; i < 8; ++i)
#pragma unroll
        for (int j = 0; j < 4; ++j) acc[i][j] = 0.f;

    const int kb = w * 256;
#pragma unroll 4
    for (int f = 0; f < 256; ++f) {
        const int k = kb + f;
        float4 xa = *(const float4*)(xs + k * 8);       // uniform b128 (rows 0-3)
        float4 xc = *(const float4*)(xs + k * 8 + 4);   // uniform b128 (rows 4-7)
        float4 wv = *(const float4*)(wa1 + (size_t)k * 256 + c0);
        float xv[8] = {xa.x, xa.y, xa.z, xa.w, xc.x, xc.y, xc.z, xc.w};
#pragma unroll
        for (int i = 0; i < 8; ++i) {
            acc[i][0] = fmaf(xv[i], wv.x, acc[i][0]);
            acc[i][1] = fmaf(xv[i], wv.y, acc[i][1]);
            acc[i][2] = fmaf(xv[i], wv.z, acc[i][2]);
            acc[i][3] = fmaf(xv[i], wv.w, acc[i][3]);
        }
    }
    __syncthreads();                     // all xs reads done -> overlay safe

    float* psum = xs;                    // [w][row][c] = w*2048 + row*256 + c
#pragma unroll
    for (int i = 0; i < 8; ++i)
        *(float4*)(psum + w * 2048 + i * 256 + c0) =
            make_float4(acc[i][0], acc[i][1], acc[i][2], acc[i][3]);
    __syncthreads();

    // ---- reduce K-partials + ba1, LN(256), relu -> h1s[c][row] ----
    const int c = tid;
    float h[8];
    {
        float bav = ba1[c];
#pragma unroll
        for (int i = 0; i < 8; ++i)
            h[i] = bav + psum[i * 256 + c] + psum[2048 + i * 256 + c]
                       + psum[4096 + i * 256 + c] + psum[6144 + i * 256 + c];
    }
#pragma unroll
    for (int i = 0; i < 8; ++i) {
        float s = h[i], s2 = h[i] * h[i];
#pragma unroll
        for (int off = 32; off >= 1; off >>= 1) {
            s  += __shfl_xor(s,  off, 64);
            s2 += __shfl_xor(s2, off, 64);
        }
        if (lane == 0) { red[w][i][0] = s; red[w][i][1] = s2; }
    }
    __syncthreads();
    {
        float gv = gla[c], bv = bla[c];
#pragma unroll
        for (int i = 0; i < 8; ++i) {
            float s  = red[0][i][0] + red[1][i][0] + red[2][i][0] + red[3][i][0];
            float s2 = red[0][i][1] + red[1][i][1] + red[2][i][1] + red[3][i][1];
            float m   = s * (1.f / 256.f);
            float var = s2 * (1.f / 256.f) - m * m;
            h1s[c * 9 + i] = fmaxf((h[i] - m) * rsqrtf(var + EPS) * gv + bv, 0.f);
        }
    }

    // ---- geo MLP (wave-local: rows r0,r1; lanes cover j = lane*2, +1) ----
    {
        const int j0 = lane * 2;
        float g00 = bg1[j0], g01 = bg1[j0 + 1];
        float g10 = g00, g11 = g01;
#pragma unroll
        for (int f = 0; f < 4; ++f) {
            float w0 = wg1[f * 128 + j0], w1 = wg1[f * 128 + j0 + 1];
            g00 = fmaf(geo_s[r0][f], w0, g00);
            g01 = fmaf(geo_s[r0][f], w1, g01);
            g10 = fmaf(geo_s[r1][f], w0, g10);
            g11 = fmaf(geo_s[r1][f], w1, g11);
        }
        // LN over 128 per row (wave-local: 64 lanes x 2 vals)
        float s0 = g00 + g01, q0 = g00 * g00 + g01 * g01;
        float s1 = g10 + g11, q1 = g10 * g10 + g11 * g11;
#pragma unroll
        for (int off = 32; off >= 1; off >>= 1) {
            s0 += __shfl_xor(s0, off, 64); q0 += __shfl_xor(q0, off, 64);
            s1 += __shfl_xor(s1, off, 64); q1 += __shfl_xor(q1, off, 64);
        }
        float m0 = s0 * (1.f / 128.f), v0 = q0 * (1.f / 128.f) - m0 * m0;
        float m1 = s1 * (1.f / 128.f), v1 = q1 * (1.f / 128.f) - m1 * m1;
        float rs0 = rsqrtf(v0 + EPS), rs1 = rsqrtf(v1 + EPS);
        float ga = glg[j0], gb = glg[j0 + 1], ba = blg[j0], bb = blg[j0 + 1];
        grl[j0 * 9 + r0]       = fmaxf((g00 - m0) * rs0 * ga + ba, 0.f);
        grl[(j0 + 1) * 9 + r0] = fmaxf((g01 - m0) * rs0 * gb + bb, 0.f);
        grl[j0 * 9 + r1]       = fmaxf((g10 - m1) * rs1 * ga + ba, 0.f);
        grl[(j0 + 1) * 9 + r1] = fmaxf((g11 - m1) * rs1 * gb + bb, 0.f);
    }
    __syncthreads();                     // h1s (cross-thread) + grl complete

    // ---- gemm2: rows r0,r1; K = 256 (h1) + 128 (grelu) ----
    float o0[4], o1[4];
    {
        float4 bb = make_float4(ba2[c0] + bg2[c0], ba2[c0 + 1] + bg2[c0 + 1],
                                ba2[c0 + 2] + bg2[c0 + 2], ba2[c0 + 3] + bg2[c0 + 3]);
        o0[0] = bb.x; o0[1] = bb.y; o0[2] = bb.z; o0[3] = bb.w;
        o1[0] = bb.x; o1[1] = bb.y; o1[2] = bb.z; o1[3] = bb.w;
    }
#pragma unroll 4
    for (int k = 0; k < 256; ++k) {
        float h0 = h1s[k * 9 + r0], h1v = h1s[k * 9 + r1];   // uniform broadcast
        float4 wv = *(const float4*)(wa2 + (size_t)k * 256 + c0);
        o0[0] = fmaf(h0, wv.x, o0[0]); o0[1] = fmaf(h0, wv.y, o0[1]);
        o0[2] = fmaf(h0, wv.z, o0[2]); o0[3] = fmaf(h0, wv.w, o0[3]);
        o1[0] = fmaf(h1v, wv.x, o1[0]); o1[1] = fmaf(h1v, wv.y, o1[1]);
        o1[2] = fmaf(h1v, wv.z, o1[2]); o1[3] = fmaf(h1v, wv.w, o1[3]);
    }
#pragma unroll 4
    for (int k = 0; k < 128; ++k) {
        float h0 = grl[k * 9 + r0], h1v = grl[k * 9 + r1];
        float4 wv = *(const float4*)(wg2 + (size_t)k * 256 + c0);
        o0[0] = fmaf(h0, wv.x, o0[0]); o0[1] = fmaf(h0, wv.y, o0[1]);
        o0[2] = fmaf(h0, wv.z, o0[2]); o0[3] = fmaf(h0, wv.w, o0[3]);
        o1[0] = fmaf(h1v, wv.x, o1[0]); o1[1] = fmaf(h1v, wv.y, o1[1]);
        o1[2] = fmaf(h1v, wv.z, o1[2]); o1[3] = fmaf(h1v, wv.w, o1[3]);
    }
    // ---- LN(256) per row (wave-local: 64 lanes x 4 cols), write emb ----
    {
        float s0 = o0[0] + o0[1] + o0[2] + o0[3];
        float q0 = o0[0]*o0[0] + o0[1]*o0[1] + o0[2]*o0[2] + o0[3]*o0[3];
        float s1 = o1[0] + o1[1] + o1[2] + o1[3];
        float q1 = o1[0]*o1[0] + o1[1]*o1[1] + o1[2]*o1[2] + o1[3]*o1[3];
#pragma unroll
        for (int off = 32; off >= 1; off >>= 1) {
            s0 += __shfl_xor(s0, off, 64); q0 += __shfl_xor(q0, off, 64);
            s1 += __shfl_xor(s1, off, 64); q1 += __shfl_xor(q1, off, 64);
        }
        float m0 = s0 * (1.f / 256.f), v0 = q0 * (1.f / 256.f) - m0 * m0;
        float m1 = s1 * (1.f / 256.f), v1 = q1 * (1.f / 256.f) - m1 * m1;
        float rs0 = rsqrtf(v0 + EPS), rs1 = rsqrtf(v1 + EPS);
#pragma unroll
        for (int j = 0; j < 4; ++j) {
            float gv = gf[c0 + j], bv = bf[c0 + j];
            emb[(c0 + j) * 9 + r0] = (o0[j] - m0) * rs0 * gv + bv;
            emb[(c0 + j) * 9 + r1] = (o1[j] - m1) * rs1 * gv + bv;
        }
    }
    __syncthreads();

    // ---- projection with this side's wc1 half -> a/c rows ----
    {
        const float* wch = wc1 + (size_t)side * (256 * 128);
        const int j0 = lane * 2;
        float p00 = 0.f, p01 = 0.f, p10 = 0.f, p11 = 0.f;
#pragma unroll 4
        for (int k = 0; k < 256; ++k) {
            float e0 = emb[k * 9 + r0], e1 = emb[k * 9 + r1];  // uniform
            float2 wv = *(const float2*)(wch + (size_t)k * 128 + j0);
            p00 = fmaf(e0, wv.x, p00); p01 = fmaf(e0, wv.y, p01);
            p10 = fmaf(e1, wv.x, p10); p11 = fmaf(e1, wv.y, p11);
        }
        float* outp = (side ? cout : aout) + ((size_t)(b * 256 + n0)) * 128;
        *(float2*)(outp + (size_t)(r0) * 128 + j0) = make_float2(p00, p01);
        *(float2*)(outp + (size_t)(r1) * 128 + j0) = make_float2(p10, p11);
    }
}

// Pairwise: logits[b,n,m] = sum_j relu(a[n,j]+c[m,j]+bc1[j])*wc2[j] + bc2
// 32x32 tile/block, 2x2 outputs/thread, grid 256.
__global__ __launch_bounds__(256) void k_pairwise(
    const float* __restrict__ a, const float* __restrict__ cmat,
    const float* __restrict__ bc1, const float* __restrict__ wc2,
    const float* __restrict__ bc2, float* __restrict__ out)
{
    __shared__ float4 a_s[32 * 33];
    __shared__ float4 c_s[32 * 33];
    const int blk = blockIdx.x;               // 4 * 8 * 8 = 256
    const int b  = blk >> 6;
    const int n0 = ((blk >> 3) & 7) << 5;
    const int m0 = (blk & 7) << 5;
    const int tid = threadIdx.x;

    const float4* a4  = (const float4*)(a    + ((size_t)b * 256 + n0) * 128);
    const float4* c4  = (const float4*)(cmat + ((size_t)b * 256 + m0) * 128);
    const float4* b14 = (const float4*)bc1;
    for (int idx = tid; idx < 1024; idx += 256) {
        int r = idx >> 5, q = idx & 31;
        float4 av = a4[r * 32 + q], bv = b14[q];
        a_s[r * 33 + q] = make_float4(av.x + bv.x, av.y + bv.y,
                                      av.z + bv.z, av.w + bv.w);
        c_s[r * 33 + q] = c4[r * 32 + q];
    }
    __syncthreads();

    const int ni = tid >> 4, mi = tid & 15;
    const float4* wp = (const float4*)wc2;
    float s00 = 0.f, s01 = 0.f, s10 = 0.f, s11 = 0.f;
#pragma unroll 4
    for (int q = 0; q < 32; ++q) {
        float4 av0 = a_s[ni * 33 + q];
        float4 av1 = a_s[(ni + 16) * 33 + q];
        float4 cv0 = c_s[mi * 33 + q];
        float4 cv1 = c_s[(mi + 16) * 33 + q];
        float4 wv  = wp[q];                                   // uniform s_load
        s00 = fmaf(fmaxf(av0.x + cv0.x, 0.f), wv.x, s00);
        s00 = fmaf(fmaxf(av0.y + cv0.y, 0.f), wv.y, s00);
        s00 = fmaf(fmaxf(av0.z + cv0.z, 0.f), wv.z, s00);
        s00 = fmaf(fmaxf(av0.w + cv0.w, 0.f), wv.w, s00);
        s01 = fmaf(fmaxf(av0.x + cv1.x, 0.f), wv.x, s01);
        s01 = fmaf(fmaxf(av0.y + cv1.y, 0.f), wv.y, s01);
        s01 = fmaf(fmaxf(av0.z + cv1.z, 0.f), wv.z, s01);
        s01 = fmaf(fmaxf(av0.w + cv1.w, 0.f), wv.w, s01);
        s10 = fmaf(fmaxf(av1.x + cv0.x, 0.f), wv.x, s10);
        s10 = fmaf(fmaxf(av1.y + cv0.y, 0.f), wv.y, s10);
        s10 = fmaf(fmaxf(av1.z + cv0.z, 0.f), wv.z, s10);
        s10 = fmaf(fmaxf(av1.w + cv0.w, 0.f), wv.w, s10);
        s11 = fmaf(fmaxf(av1.x + cv1.x, 0.f), wv.x, s11);
        s11 = fmaf(fmaxf(av1.y + cv1.y, 0.f), wv.y, s11);
        s11 = fmaf(fmaxf(av1.z + cv1.z, 0.f), wv.z, s11);
        s11 = fmaf(fmaxf(av1.w + cv1.w, 0.f), wv.w, s11);
    }
    const float b2 = bc2[0];
    float* ob = out + ((size_t)b * 256 + n0) * 256 + m0;
    ob[(size_t)ni * 256 + mi]               = s00 + b2;
    ob[(size_t)ni * 256 + mi + 16]          = s01 + b2;
    ob[(size_t)(ni + 16) * 256 + mi]        = s10 + b2;
    ob[(size_t)(ni + 16) * 256 + mi + 16]   = s11 + b2;
}

extern "C" void kernel_launch(void* const* d_in, const int* in_sizes, int n_in,
                              void* d_out, int out_size, void* d_ws, size_t ws_size,
                              hipStream_t stream)
{
    const float* tracks = (const float*)d_in[0];
    const float* dets   = (const float*)d_in[1];
    const float* wa1 = (const float*)d_in[2];
    const float* ba1 = (const float*)d_in[3];
    const float* gla = (const float*)d_in[4];
    const float* bla = (const float*)d_in[5];
    const float* wa2 = (const float*)d_in[6];
    const float* ba2 = (const float*)d_in[7];
    const float* wg1 = (const float*)d_in[8];
    const float* bg1 = (const float*)d_in[9];
    const float* glg = (const float*)d_in[10];
    const float* blg = (const float*)d_in[11];
    const float* wg2 = (const float*)d_in[12];
    const float* bg2 = (const float*)d_in[13];
    const float* gf  = (const float*)d_in[14];
    const float* bf  = (const float*)d_in[15];
    // d_in[16..23]: attention weights — dead code in reference.
    const float* wc1 = (const float*)d_in[24];
    const float* bc1 = (const float*)d_in[25];
    const float* wc2 = (const float*)d_in[26];
    const float* bc2 = (const float*)d_in[27];
    float* out = (float*)d_out;
    float* ws  = (float*)d_ws;

    float* aa = ws;                    // 4*256*128
    float* cc = ws + 131072;           // 4*256*128

    hipLaunchKernelGGL(k_encode, dim3(256), dim3(256), 0, stream,
                       tracks, dets, wa1, ba1, gla, bla, wa2, ba2,
                       wg1, bg1, glg, blg, wg2, bg2, gf, bf, wc1, aa, cc);
    hipLaunchKernelGGL(k_pairwise, dim3(256), dim3(256), 0, stream,
                       aa, cc, bc1, wc2, bc2, out);
}

// Round 6
// 169.001 us; speedup vs baseline: 1.1755x; 1.1755x over previous
//
#include <hip/hip_runtime.h>

#define EPS 1e-5f

// ===========================================================================
// ws layout (float offsets):
//   part  @ 0       : 8 * 2048 * 256 = 4,194,304 (16 MB; gemm2 reuses 6 slices)
//   h1ext @ 4194304 : 2048 * 384    =   786,432 (3 MB)  row-major [g][384]
//   aout  @ 4980736 : 4*256*128     =   131,072
//   cout  @ 5111808 : 4*256*128     =   131,072
// Attention branch of the reference is dead code (attn_out unused) — skipped.
//
// Round-6 fix: both GEMMs get an 8-deep double-buffered register prefetch of
// the weight stream (the R4/R5 stall source: <=2 outstanding loads/wave could
// not cover ~200-900cy L2/HBM latency; 8 KB/wave in flight can). Grid 1024/768
// with __launch_bounds__(256,4) keeps 4 waves/SIMD of TLP on top.
// ===========================================================================

// GEMM1 partial: part[ksi][g][c] = sum_{k in 128-slice} x[g][k] * wa1[k][c]
// grid 1024 = 128 row-tiles(16 rows) x 8 k-slices (ksi = blk&7 -> XCD-affine).
__global__ __launch_bounds__(256, 4) void k_gemm1(
    const float* __restrict__ tracks, const float* __restrict__ dets,
    const float* __restrict__ wa1, float* __restrict__ part)
{
    __shared__ float xs[128 * 16];     // [f][r]
    const int blk = blockIdx.x;
    const int rt  = blk >> 3;
    const int ksi = blk & 7;
    const int g0  = rt * 16;
    const int side = g0 >> 10, b = (g0 >> 8) & 3, n0 = g0 & 255;
    const float* xb = (side ? dets : tracks) + (size_t)b * (1028 * 256);
    const int k0 = ksi * 128;
    const int tid = threadIdx.x;
    const int w   = tid >> 6;          // wave -> row quad (rows w*4..w*4+3)
    const int c0  = (tid & 63) * 4;    // lane -> 4 output cols

    // stage via float4: wave instr covers 16 full 64B lines; n0 is 16-aligned
    for (int t = tid; t < 512; t += 256) {
        int f = t >> 2, r4 = (t & 3) << 2;
        *(float4*)(xs + f * 16 + r4) =
            *(const float4*)(xb + (size_t)(k0 + f) * 256 + n0 + r4);
    }
    __syncthreads();

    float acc[4][4];
#pragma unroll
    for (int i = 0; i < 4; ++i)
#pragma unroll
        for (int j = 0; j < 4; ++j) acc[i][j] = 0.f;

    const float* wptr = wa1 + (size_t)k0 * 256 + c0;
    float4 wb[2][8];
#pragma unroll
    for (int j = 0; j < 8; ++j)
        wb[0][j] = *(const float4*)(wptr + (size_t)j * 256);

#pragma unroll
    for (int bb = 0; bb < 16; ++bb) {          // 16 batches x 8 k
        const int cur = bb & 1, nxt = cur ^ 1;
        if (bb < 15) {
#pragma unroll
            for (int j = 0; j < 8; ++j)
                wb[nxt][j] =
                    *(const float4*)(wptr + (size_t)((bb + 1) * 8 + j) * 256);
        }
#pragma unroll
        for (int j = 0; j < 8; ++j) {
            const int f = bb * 8 + j;
            float4 xv = *(const float4*)(xs + f * 16 + w * 4);  // uniform b128
            float4 wv = wb[cur][j];
            acc[0][0] = fmaf(xv.x, wv.x, acc[0][0]);
            acc[0][1] = fmaf(xv.x, wv.y, acc[0][1]);
            acc[0][2] = fmaf(xv.x, wv.z, acc[0][2]);
            acc[0][3] = fmaf(xv.x, wv.w, acc[0][3]);
            acc[1][0] = fmaf(xv.y, wv.x, acc[1][0]);
            acc[1][1] = fmaf(xv.y, wv.y, acc[1][1]);
            acc[1][2] = fmaf(xv.y, wv.z, acc[1][2]);
            acc[1][3] = fmaf(xv.y, wv.w, acc[1][3]);
            acc[2][0] = fmaf(xv.z, wv.x, acc[2][0]);
            acc[2][1] = fmaf(xv.z, wv.y, acc[2][1]);
            acc[2][2] = fmaf(xv.z, wv.z, acc[2][2]);
            acc[2][3] = fmaf(xv.z, wv.w, acc[2][3]);
            acc[3][0] = fmaf(xv.w, wv.x, acc[3][0]);
            acc[3][1] = fmaf(xv.w, wv.y, acc[3][1]);
            acc[3][2] = fmaf(xv.w, wv.z, acc[3][2]);
            acc[3][3] = fmaf(xv.w, wv.w, acc[3][3]);
        }
    }
    float* pb = part + ((size_t)ksi * 2048 + g0 + w * 4) * 256 + c0;
#pragma unroll
    for (int i = 0; i < 4; ++i)
        *(float4*)(pb + (size_t)i * 256) =
            make_float4(acc[i][0], acc[i][1], acc[i][2], acc[i][3]);
}

// Reduce 8 partials + ba1, LN(256), relu -> h1ext[g][0..255];
// geo MLP + LN(128) + relu -> h1ext[g][256..383].  grid 512 x 4 rows.
__global__ __launch_bounds__(256) void k_reduce1(
    const float* __restrict__ tracks, const float* __restrict__ dets,
    const float* __restrict__ part,
    const float* __restrict__ ba1, const float* __restrict__ gla,
    const float* __restrict__ bla,
    const float* __restrict__ wg1, const float* __restrict__ bg1,
    const float* __restrict__ glg, const float* __restrict__ blg,
    float* __restrict__ h1ext)
{
    __shared__ float red[4][4][2];
    __shared__ float geo_s[4][4];
    const int blk = blockIdx.x;
    const int g0 = blk * 4;
    const int side = g0 >> 10, b = (g0 >> 8) & 3, n0 = g0 & 255;
    const float* xb = (side ? dets : tracks) + (size_t)b * (1028 * 256);
    const int tid = threadIdx.x, wave = tid >> 6, lane = tid & 63, c = tid;

    if (tid < 16)
        geo_s[tid >> 2][tid & 3] =
            xb[(size_t)(1024 + (tid & 3)) * 256 + n0 + (tid >> 2)];

    float h[4];
#pragma unroll
    for (int i = 0; i < 4; ++i) {
        float s = ba1[c];
#pragma unroll
        for (int s8 = 0; s8 < 8; ++s8)
            s += part[((size_t)s8 * 2048 + g0 + i) * 256 + c];
        h[i] = s;
    }
#pragma unroll
    for (int i = 0; i < 4; ++i) {
        float s = h[i], s2 = h[i] * h[i];
#pragma unroll
        for (int off = 32; off >= 1; off >>= 1) {
            s  += __shfl_xor(s,  off, 64);
            s2 += __shfl_xor(s2, off, 64);
        }
        if (lane == 0) { red[wave][i][0] = s; red[wave][i][1] = s2; }
    }
    __syncthreads();
    {
        float gv = gla[c], bv = bla[c];
#pragma unroll
        for (int i = 0; i < 4; ++i) {
            float s  = red[0][i][0] + red[1][i][0] + red[2][i][0] + red[3][i][0];
            float s2 = red[0][i][1] + red[1][i][1] + red[2][i][1] + red[3][i][1];
            float m   = s * (1.f / 256.f);
            float var = s2 * (1.f / 256.f) - m * m;
            h1ext[(size_t)(g0 + i) * 384 + c] =
                fmaxf((h[i] - m) * rsqrtf(var + EPS) * gv + bv, 0.f);
        }
    }
    __syncthreads();   // red reads done before geo phase overwrites

    float gh[4];
    if (tid < 128) {
        const int j = tid;
#pragma unroll
        for (int i = 0; i < 4; ++i) {
            float s = bg1[j];
#pragma unroll
            for (int f = 0; f < 4; ++f)
                s = fmaf(geo_s[i][f], wg1[f * 128 + j], s);
            gh[i] = s;
        }
#pragma unroll
        for (int i = 0; i < 4; ++i) {
            float s = gh[i], s2 = gh[i] * gh[i];
#pragma unroll
            for (int off = 32; off >= 1; off >>= 1) {
                s  += __shfl_xor(s,  off, 64);
                s2 += __shfl_xor(s2, off, 64);
            }
            if (lane == 0) { red[wave][i][0] = s; red[wave][i][1] = s2; }
        }
    }
    __syncthreads();
    if (tid < 128) {
        const int j = tid;
        float gv = glg[j], bv = blg[j];
#pragma unroll
        for (int i = 0; i < 4; ++i) {
            float s  = red[0][i][0] + red[1][i][0];
            float s2 = red[0][i][1] + red[1][i][1];
            float m   = s * (1.f / 128.f);
            float var = s2 * (1.f / 128.f) - m * m;
            h1ext[(size_t)(g0 + i) * 384 + 256 + j] =
                fmaxf((gh[i] - m) * rsqrtf(var + EPS) * gv + bv, 0.f);
        }
    }
}

// GEMM2 partial: part[sl][g][c] = sum_{k in 64-slice} h1ext[g][k] * W[k][c]
// K=384 total, 6 slices of 64. grid 768 = 128 row-tiles x 6 slices.
__global__ __launch_bounds__(256, 4) void k_gemm2(
    const float* __restrict__ h1ext,
    const float* __restrict__ wa2, const float* __restrict__ wg2,
    float* __restrict__ part)
{
    __shared__ float xs[64 * 16];
    const int blk = blockIdx.x;
    const int rt = blk / 6, sl = blk - rt * 6;
    const int g0 = rt * 16;
    const int k0 = sl * 64;
    const int tid = threadIdx.x;
    const int w   = tid >> 6;
    const int c0  = (tid & 63) * 4;
    const float* Wb = (k0 < 256) ? (wa2 + (size_t)k0 * 256)
                                 : (wg2 + (size_t)(k0 - 256) * 256);

    for (int idx = tid; idx < 1024; idx += 256) {
        int f = idx >> 4, r = idx & 15;
        xs[f * 16 + r] = h1ext[(size_t)(g0 + r) * 384 + k0 + f];
    }
    __syncthreads();

    float acc[4][4];
#pragma unroll
    for (int i = 0; i < 4; ++i)
#pragma unroll
        for (int j = 0; j < 4; ++j) acc[i][j] = 0.f;

    const float* wptr = Wb + c0;
    float4 wb[2][8];
#pragma unroll
    for (int j = 0; j < 8; ++j)
        wb[0][j] = *(const float4*)(wptr + (size_t)j * 256);

#pragma unroll
    for (int bb = 0; bb < 8; ++bb) {           // 8 batches x 8 k
        const int cur = bb & 1, nxt = cur ^ 1;
        if (bb < 7) {
#pragma unroll
            for (int j = 0; j < 8; ++j)
                wb[nxt][j] =
                    *(const float4*)(wptr + (size_t)((bb + 1) * 8 + j) * 256);
        }
#pragma unroll
        for (int j = 0; j < 8; ++j) {
            const int f = bb * 8 + j;
            float4 xv = *(const float4*)(xs + f * 16 + w * 4);  // uniform b128
            float4 wv = wb[cur][j];
            acc[0][0] = fmaf(xv.x, wv.x, acc[0][0]);
            acc[0][1] = fmaf(xv.x, wv.y, acc[0][1]);
            acc[0][2] = fmaf(xv.x, wv.z, acc[0][2]);
            acc[0][3] = fmaf(xv.x, wv.w, acc[0][3]);
            acc[1][0] = fmaf(xv.y, wv.x, acc[1][0]);
            acc[1][1] = fmaf(xv.y, wv.y, acc[1][1]);
            acc[1][2] = fmaf(xv.y, wv.z, acc[1][2]);
            acc[1][3] = fmaf(xv.y, wv.w, acc[1][3]);
            acc[2][0] = fmaf(xv.z, wv.x, acc[2][0]);
            acc[2][1] = fmaf(xv.z, wv.y, acc[2][1]);
            acc[2][2] = fmaf(xv.z, wv.z, acc[2][2]);
            acc[2][3] = fmaf(xv.z, wv.w, acc[2][3]);
            acc[3][0] = fmaf(xv.w, wv.x, acc[3][0]);
            acc[3][1] = fmaf(xv.w, wv.y, acc[3][1]);
            acc[3][2] = fmaf(xv.w, wv.z, acc[3][2]);
            acc[3][3] = fmaf(xv.w, wv.w, acc[3][3]);
        }
    }
    float* pb = part + ((size_t)sl * 2048 + g0 + w * 4) * 256 + c0;
#pragma unroll
    for (int i = 0; i < 4; ++i)
        *(float4*)(pb + (size_t)i * 256) =
            make_float4(acc[i][0], acc[i][1], acc[i][2], acc[i][3]);
}

// Reduce 6 partials + ba2+bg2, LN(gf,bf), project with wc1 half -> a/c rows.
// grid 512 x 4 rows.
__global__ __launch_bounds__(256) void k_reduce2(
    const float* __restrict__ part,
    const float* __restrict__ ba2, const float* __restrict__ bg2,
    const float* __restrict__ gf,  const float* __restrict__ bf,
    const float* __restrict__ wc1,
    float* __restrict__ aout, float* __restrict__ cout)
{
    __shared__ float red[4][4][2];
    __shared__ float emb[256 * 4];        // [k][row]
    __shared__ float psum[2][4][128];
    const int blk = blockIdx.x;
    const int g0 = blk * 4;
    const int side = g0 >> 10, b = (g0 >> 8) & 3, nin = g0 & 255;
    const int tid = threadIdx.x, wave = tid >> 6, lane = tid & 63, c = tid;

    float h2[4];
#pragma unroll
    for (int i = 0; i < 4; ++i) {
        float s = ba2[c] + bg2[c];
#pragma unroll
        for (int sl = 0; sl < 6; ++sl)
            s += part[((size_t)sl * 2048 + g0 + i) * 256 + c];
        h2[i] = s;
    }
#pragma unroll
    for (int i = 0; i < 4; ++i) {
        float s = h2[i], s2 = h2[i] * h2[i];
#pragma unroll
        for (int off = 32; off >= 1; off >>= 1) {
            s  += __shfl_xor(s,  off, 64);
            s2 += __shfl_xor(s2, off, 64);
        }
        if (lane == 0) { red[wave][i][0] = s; red[wave][i][1] = s2; }
    }
    __syncthreads();
    {
        float gv = gf[c], bv = bf[c];
        float e[4];
#pragma unroll
        for (int i = 0; i < 4; ++i) {
            float s  = red[0][i][0] + red[1][i][0] + red[2][i][0] + red[3][i][0];
            float s2 = red[0][i][1] + red[1][i][1] + red[2][i][1] + red[3][i][1];
            float m   = s * (1.f / 256.f);
            float var = s2 * (1.f / 256.f) - m * m;
            e[i] = (h2[i] - m) * rsqrtf(var + EPS) * gv + bv;
        }
        *(float4*)(emb + (size_t)c * 4) = make_float4(e[0], e[1], e[2], e[3]);
    }
    __syncthreads();

    const int half = tid >> 7, j = tid & 127;
    const float* wch = wc1 + (size_t)side * (256 * 128);
    float a4[4] = {0.f, 0.f, 0.f, 0.f};
#pragma unroll 4
    for (int k = 0; k < 128; ++k) {
        int kk = half * 128 + k;
        float w = wch[(size_t)kk * 128 + j];                  // coalesced
        float4 ev = *(const float4*)(emb + kk * 4);           // broadcast
        a4[0] = fmaf(ev.x, w, a4[0]); a4[1] = fmaf(ev.y, w, a4[1]);
        a4[2] = fmaf(ev.z, w, a4[2]); a4[3] = fmaf(ev.w, w, a4[3]);
    }
#pragma unroll
    for (int i = 0; i < 4; ++i) psum[half][i][j] = a4[i];
    __syncthreads();

    float* outp = (side ? cout : aout) + ((size_t)b * 256 + nin) * 128;
    for (int idx = tid; idx < 512; idx += 256) {
        int i = idx >> 7, jo = idx & 127;
        outp[(size_t)i * 128 + jo] = psum[0][i][jo] + psum[1][i][jo];
    }
}

// Pairwise: logits[b,n,m] = sum_j relu(a[n,j]+c[m,j]+bc1[j])*wc2[j] + bc2
// grid 1024 (4 blk/CU -> 4 waves/SIMD), 16x16 tile, 1 output/thread.
__global__ __launch_bounds__(256) void k_pairwise(
    const float* __restrict__ a, const float* __restrict__ cmat,
    const float* __restrict__ bc1, const float* __restrict__ wc2,
    const float* __restrict__ bc2, float* __restrict__ out)
{
    __shared__ float4 a_s[16 * 33];
    __shared__ float4 c_s[16 * 33];
    const int blk = blockIdx.x;
    const int b  = blk >> 8;
    const int n0 = ((blk >> 4) & 15) << 4;
    const int m0 = (blk & 15) << 4;
    const int tid = threadIdx.x;

    const float4* a4  = (const float4*)(a    + ((size_t)b * 256 + n0) * 128);
    const float4* c4  = (const float4*)(cmat + ((size_t)b * 256 + m0) * 128);
    const float4* b14 = (const float4*)bc1;
    for (int idx = tid; idx < 512; idx += 256) {
        int r = idx >> 5, q = idx & 31;
        float4 av = a4[r * 32 + q], bv = b14[q];
        a_s[r * 33 + q] = make_float4(av.x + bv.x, av.y + bv.y,
                                      av.z + bv.z, av.w + bv.w);
        c_s[r * 33 + q] = c4[r * 32 + q];
    }
    __syncthreads();

    const int ni = tid >> 4, mi = tid & 15;
    const float4* wp = (const float4*)wc2;
    float acc = bc2[0];
#pragma unroll 8
    for (int q = 0; q < 32; ++q) {
        float4 av = a_s[ni * 33 + q];
        float4 cv = c_s[mi * 33 + q];
        float4 wv = wp[q];                                    // uniform s_load
        acc = fmaf(fmaxf(av.x + cv.x, 0.f), wv.x, acc);
        acc = fmaf(fmaxf(av.y + cv.y, 0.f), wv.y, acc);
        acc = fmaf(fmaxf(av.z + cv.z, 0.f), wv.z, acc);
        acc = fmaf(fmaxf(av.w + cv.w, 0.f), wv.w, acc);
    }
    out[((size_t)b * 256 + n0 + ni) * 256 + m0 + mi] = acc;
}

extern "C" void kernel_launch(void* const* d_in, const int* in_sizes, int n_in,
                              void* d_out, int out_size, void* d_ws, size_t ws_size,
                              hipStream_t stream)
{
    const float* tracks = (const float*)d_in[0];
    const float* dets   = (const float*)d_in[1];
    const float* wa1 = (const float*)d_in[2];
    const float* ba1 = (const float*)d_in[3];
    const float* gla = (const float*)d_in[4];
    const float* bla = (const float*)d_in[5];
    const float* wa2 = (const float*)d_in[6];
    const float* ba2 = (const float*)d_in[7];
    const float* wg1 = (const float*)d_in[8];
    const float* bg1 = (const float*)d_in[9];
    const float* glg = (const float*)d_in[10];
    const float* blg = (const float*)d_in[11];
    const float* wg2 = (const float*)d_in[12];
    const float* bg2 = (const float*)d_in[13];
    const float* gf  = (const float*)d_in[14];
    const float* bf  = (const float*)d_in[15];
    // d_in[16..23]: attention weights — dead code in reference.
    const float* wc1 = (const float*)d_in[24];
    const float* bc1 = (const float*)d_in[25];
    const float* wc2 = (const float*)d_in[26];
    const float* bc2 = (const float*)d_in[27];
    float* out = (float*)d_out;
    float* ws  = (float*)d_ws;

    float* part  = ws;
    float* h1ext = ws + 4194304;
    float* aa    = ws + 4980736;
    float* cc    = ws + 5111808;

    hipLaunchKernelGGL(k_gemm1, dim3(1024), dim3(256), 0, stream,
                       tracks, dets, wa1, part);
    hipLaunchKernelGGL(k_reduce1, dim3(512), dim3(256), 0, stream,
                       tracks, dets, part, ba1, gla, bla,
                       wg1, bg1, glg, blg, h1ext);
    hipLaunchKernelGGL(k_gemm2, dim3(768), dim3(256), 0, stream,
                       h1ext, wa2, wg2, part);
    hipLaunchKernelGGL(k_reduce2, dim3(512), dim3(256), 0, stream,
                       part, ba2, bg2, gf, bf, wc1, aa, cc);
    hipLaunchKernelGGL(k_pairwise, dim3(1024), dim3(256), 0, stream,
                       aa, cc, bc1, wc2, bc2, out);
}

// Round 7
// 160.319 us; speedup vs baseline: 1.2392x; 1.0542x over previous
//
#include <hip/hip_runtime.h>

#define EPS 1e-5f

// ===========================================================================
// 3-kernel pipeline (round 7):
//   k_gemm1   : x @ wa1 partials, K-split 8, 32-row tiles. grid 512.
//   k_tail    : reduce+LN+relu, geo-MLP+LN+relu, gemm2 (K-split by wave),
//               LN, wc1 projection -> a/c. grid 512 (4-row tiles).
//   k_pairwise: relu(a+c+bc1)@wc2 logits. grid 1024.
// ws layout (float offsets):
//   part @ 0       : 8 * 2048 * 256 = 4,194,304 (16 MB)
//   aout @ 4980736 : 4*256*128
//   cout @ 5111808 : 4*256*128
// Attention branch of the reference is dead code (attn_out unused) — skipped.
// ===========================================================================

// GEMM1 partial: part[ksi][g][c] = sum_{k in 128-slice} x[g][k] * wa1[k][c]
// grid 512 = 64 row-tiles(32 rows) x 8 k-slices. Wave owns an 8-row group
// (2 uniform ds_read_b128 per k), lane owns 4 cols (float4 weight load,
// 8-deep double-buffered register prefetch). 0.25 B/FLOP -> VALU-bound.
__global__ __launch_bounds__(256, 2) void k_gemm1(
    const float* __restrict__ tracks, const float* __restrict__ dets,
    const float* __restrict__ wa1, float* __restrict__ part)
{
    __shared__ __align__(16) float xs[128 * 32];   // [f][r] 16KB
    const int blk = blockIdx.x;
    const int rt  = blk >> 3;
    const int ksi = blk & 7;
    const int g0  = rt * 32;
    const int side = g0 >> 10, b = (g0 >> 8) & 3, n0 = g0 & 255;
    const float* xb = (side ? dets : tracks) + (size_t)b * (1028 * 256);
    const int k0 = ksi * 128;
    const int tid = threadIdx.x;
    const int w   = tid >> 6;          // wave -> rows w*8 .. w*8+7
    const int c0  = (tid & 63) * 4;    // lane -> 4 output cols

    // stage 128 x 32 via float4 (full 64B lines, n0 is 32-aligned)
    for (int t = tid; t < 1024; t += 256) {
        int f = t >> 3, r4 = (t & 7) << 2;
        *(float4*)(xs + f * 32 + r4) =
            *(const float4*)(xb + (size_t)(k0 + f) * 256 + n0 + r4);
    }
    __syncthreads();

    float acc[8][4];
#pragma unroll
    for (int i = 0; i < 8; ++i)
#pragma unroll
        for (int j = 0; j < 4; ++j) acc[i][j] = 0.f;

    const float* wptr = wa1 + (size_t)k0 * 256 + c0;
    float4 wb[2][8];
#pragma unroll
    for (int j = 0; j < 8; ++j)
        wb[0][j] = *(const float4*)(wptr + (size_t)j * 256);

#pragma unroll
    for (int bb = 0; bb < 16; ++bb) {          // 16 batches x 8 k
        const int cur = bb & 1, nxt = cur ^ 1;
        if (bb < 15) {
#pragma unroll
            for (int j = 0; j < 8; ++j)
                wb[nxt][j] =
                    *(const float4*)(wptr + (size_t)((bb + 1) * 8 + j) * 256);
        }
#pragma unroll
        for (int j = 0; j < 8; ++j) {
            const int f = bb * 8 + j;
            float4 x0 = *(const float4*)(xs + f * 32 + w * 8);      // uniform
            float4 x1 = *(const float4*)(xs + f * 32 + w * 8 + 4);  // uniform
            float4 wv = wb[cur][j];
            float xv[8] = {x0.x, x0.y, x0.z, x0.w, x1.x, x1.y, x1.z, x1.w};
#pragma unroll
            for (int i = 0; i < 8; ++i) {
                acc[i][0] = fmaf(xv[i], wv.x, acc[i][0]);
                acc[i][1] = fmaf(xv[i], wv.y, acc[i][1]);
                acc[i][2] = fmaf(xv[i], wv.z, acc[i][2]);
                acc[i][3] = fmaf(xv[i], wv.w, acc[i][3]);
            }
        }
    }
    float* pb = part + ((size_t)ksi * 2048 + g0 + w * 8) * 256 + c0;
#pragma unroll
    for (int i = 0; i < 8; ++i)
        *(float4*)(pb + (size_t)i * 256) =
            make_float4(acc[i][0], acc[i][1], acc[i][2], acc[i][3]);
}

// Fused tail: per 4-row tile — reduce 8 partials + ba1, LN(256), relu;
// geo-MLP + LN(128) + relu; gemm2 K=384 split across waves; LN(gf,bf);
// wc1-half projection -> a/c rows.  grid 512.
__global__ __launch_bounds__(256, 2) void k_tail(
    const float* __restrict__ tracks, const float* __restrict__ dets,
    const float* __restrict__ part,
    const float* __restrict__ ba1, const float* __restrict__ gla,
    const float* __restrict__ bla,
    const float* __restrict__ wg1, const float* __restrict__ bg1,
    const float* __restrict__ glg, const float* __restrict__ blg,
    const float* __restrict__ wa2, const float* __restrict__ ba2,
    const float* __restrict__ wg2, const float* __restrict__ bg2,
    const float* __restrict__ gf,  const float* __restrict__ bf,
    const float* __restrict__ wc1,
    float* __restrict__ aout, float* __restrict__ cout)
{
    __shared__ __align__(16) float h1e[384 * 4];    // [k][row] 6KB
    __shared__ __align__(16) float psum[16 * 256];  // [w*4+row][c] 16KB
    __shared__ __align__(16) float emb[256 * 4];    // [k][row] 4KB
    __shared__ float ps2[2][4][128];
    __shared__ float red[4][4][2];
    __shared__ float geo_s[4][4];

    const int blk = blockIdx.x;
    const int g0 = blk * 4;
    const int side = g0 >> 10, b = (g0 >> 8) & 3, n0 = g0 & 255;
    const float* xb = (side ? dets : tracks) + (size_t)b * (1028 * 256);
    const int tid = threadIdx.x, w = tid >> 6, lane = tid & 63, c = tid;

    if (tid < 16)
        geo_s[tid >> 2][tid & 3] =
            xb[(size_t)(1024 + (tid & 3)) * 256 + n0 + (tid >> 2)];

    // ---- 1: reduce 8 K-partials + ba1 ----
    float h[4];
#pragma unroll
    for (int i = 0; i < 4; ++i) {
        float s = ba1[c];
#pragma unroll
        for (int s8 = 0; s8 < 8; ++s8)
            s += part[((size_t)s8 * 2048 + g0 + i) * 256 + c];
        h[i] = s;
    }
#pragma unroll
    for (int i = 0; i < 4; ++i) {
        float s = h[i], s2 = h[i] * h[i];
#pragma unroll
        for (int off = 32; off >= 1; off >>= 1) {
            s  += __shfl_xor(s,  off, 64);
            s2 += __shfl_xor(s2, off, 64);
        }
        if (lane == 0) { red[w][i][0] = s; red[w][i][1] = s2; }
    }
    __syncthreads();
    {
        float gv = gla[c], bv = bla[c];
#pragma unroll
        for (int i = 0; i < 4; ++i) {
            float s  = red[0][i][0] + red[1][i][0] + red[2][i][0] + red[3][i][0];
            float s2 = red[0][i][1] + red[1][i][1] + red[2][i][1] + red[3][i][1];
            float m   = s * (1.f / 256.f);
            float var = s2 * (1.f / 256.f) - m * m;
            h1e[c * 4 + i] =
                fmaxf((h[i] - m) * rsqrtf(var + EPS) * gv + bv, 0.f);
        }
    }
    __syncthreads();   // red consumers done

    // ---- 2: geo MLP + LN(128) + relu -> h1e[256..384) ----
    float gh[4];
    if (tid < 128) {
        const int j = tid;
#pragma unroll
        for (int i = 0; i < 4; ++i) {
            float s = bg1[j];
#pragma unroll
            for (int f = 0; f < 4; ++f)
                s = fmaf(geo_s[i][f], wg1[f * 128 + j], s);
            gh[i] = s;
        }
#pragma unroll
        for (int i = 0; i < 4; ++i) {
            float s = gh[i], s2 = gh[i] * gh[i];
#pragma unroll
            for (int off = 32; off >= 1; off >>= 1) {
                s  += __shfl_xor(s,  off, 64);
                s2 += __shfl_xor(s2, off, 64);
            }
            if (lane == 0) { red[w][i][0] = s; red[w][i][1] = s2; }
        }
    }
    __syncthreads();
    if (tid < 128) {
        const int j = tid;
        float gv = glg[j], bv = blg[j];
#pragma unroll
        for (int i = 0; i < 4; ++i) {
            float s  = red[0][i][0] + red[1][i][0];
            float s2 = red[0][i][1] + red[1][i][1];
            float m   = s * (1.f / 128.f);
            float var = s2 * (1.f / 128.f) - m * m;
            h1e[(256 + j) * 4 + i] =
                fmaxf((gh[i] - m) * rsqrtf(var + EPS) * gv + bv, 0.f);
        }
    }
    __syncthreads();   // h1e complete

    // ---- 3: gemm2, K-split by wave: wa2 rows [w*64,w*64+64),
    //         wg2 rows [w*32,w*32+32). lane -> 4 cols. ----
    const int c0 = lane * 4;
    float acc[4][4];
#pragma unroll
    for (int i = 0; i < 4; ++i)
#pragma unroll
        for (int j = 0; j < 4; ++j) acc[i][j] = 0.f;

    {
        const int ka = w * 64;
#pragma unroll 4
        for (int k = 0; k < 64; ++k) {
            float4 xv = *(const float4*)(h1e + (ka + k) * 4);      // uniform
            float4 wv = *(const float4*)(wa2 + (size_t)(ka + k) * 256 + c0);
#pragma unroll
            for (int i = 0; i < 4; ++i) {
                float x = (&xv.x)[i];
                acc[i][0] = fmaf(x, wv.x, acc[i][0]);
                acc[i][1] = fmaf(x, wv.y, acc[i][1]);
                acc[i][2] = fmaf(x, wv.z, acc[i][2]);
                acc[i][3] = fmaf(x, wv.w, acc[i][3]);
            }
        }
        const int kg = w * 32;
#pragma unroll 4
        for (int k = 0; k < 32; ++k) {
            float4 xv = *(const float4*)(h1e + (256 + kg + k) * 4);  // uniform
            float4 wv = *(const float4*)(wg2 + (size_t)(kg + k) * 256 + c0);
#pragma unroll
            for (int i = 0; i < 4; ++i) {
                float x = (&xv.x)[i];
                acc[i][0] = fmaf(x, wv.x, acc[i][0]);
                acc[i][1] = fmaf(x, wv.y, acc[i][1]);
                acc[i][2] = fmaf(x, wv.z, acc[i][2]);
                acc[i][3] = fmaf(x, wv.w, acc[i][3]);
            }
        }
    }
#pragma unroll
    for (int i = 0; i < 4; ++i)
        *(float4*)(psum + (w * 4 + i) * 256 + c0) =
            make_float4(acc[i][0], acc[i][1], acc[i][2], acc[i][3]);
    __syncthreads();

    // ---- 4: combine wave partials + ba2+bg2, LN(gf,bf) -> emb ----
    float h2[4];
#pragma unroll
    for (int i = 0; i < 4; ++i) {
        float s = ba2[c] + bg2[c];
#pragma unroll
        for (int w4 = 0; w4 < 4; ++w4)
            s += psum[(w4 * 4 + i) * 256 + c];
        h2[i] = s;
    }
#pragma unroll
    for (int i = 0; i < 4; ++i) {
        float s = h2[i], s2 = h2[i] * h2[i];
#pragma unroll
        for (int off = 32; off >= 1; off >>= 1) {
            s  += __shfl_xor(s,  off, 64);
            s2 += __shfl_xor(s2, off, 64);
        }
        if (lane == 0) { red[w][i][0] = s; red[w][i][1] = s2; }
    }
    __syncthreads();
    {
        float gv = gf[c], bv = bf[c];
#pragma unroll
        for (int i = 0; i < 4; ++i) {
            float s  = red[0][i][0] + red[1][i][0] + red[2][i][0] + red[3][i][0];
            float s2 = red[0][i][1] + red[1][i][1] + red[2][i][1] + red[3][i][1];
            float m   = s * (1.f / 256.f);
            float var = s2 * (1.f / 256.f) - m * m;
            emb[c * 4 + i] = (h2[i] - m) * rsqrtf(var + EPS) * gv + bv;
        }
    }
    __syncthreads();

    // ---- 5: projection with this side's wc1 half -> a/c rows ----
    const int half = tid >> 7, j = tid & 127;
    const float* wch = wc1 + (size_t)side * (256 * 128);
    float a4[4] = {0.f, 0.f, 0.f, 0.f};
#pragma unroll 4
    for (int k = 0; k < 128; ++k) {
        int kk = half * 128 + k;
        float wv = wch[(size_t)kk * 128 + j];                 // coalesced
        float4 ev = *(const float4*)(emb + kk * 4);           // broadcast
        a4[0] = fmaf(ev.x, wv, a4[0]); a4[1] = fmaf(ev.y, wv, a4[1]);
        a4[2] = fmaf(ev.z, wv, a4[2]); a4[3] = fmaf(ev.w, wv, a4[3]);
    }
#pragma unroll
    for (int i = 0; i < 4; ++i) ps2[half][i][j] = a4[i];
    __syncthreads();

    float* outp = (side ? cout : aout) + ((size_t)b * 256 + n0) * 128;
    for (int idx = tid; idx < 512; idx += 256) {
        int i = idx >> 7, jo = idx & 127;
        outp[(size_t)i * 128 + jo] = ps2[0][i][jo] + ps2[1][i][jo];
    }
}

// Pairwise: logits[b,n,m] = sum_j relu(a[n,j]+c[m,j]+bc1[j])*wc2[j] + bc2
// grid 1024 (4 blk/CU), 16x16 tile, 1 output/thread.
__global__ __launch_bounds__(256) void k_pairwise(
    const float* __restrict__ a, const float* __restrict__ cmat,
    const float* __restrict__ bc1, const float* __restrict__ wc2,
    const float* __restrict__ bc2, float* __restrict__ out)
{
    __shared__ float4 a_s[16 * 33];
    __shared__ float4 c_s[16 * 33];
    const int blk = blockIdx.x;
    const int b  = blk >> 8;
    const int n0 = ((blk >> 4) & 15) << 4;
    const int m0 = (blk & 15) << 4;
    const int tid = threadIdx.x;

    const float4* a4  = (const float4*)(a    + ((size_t)b * 256 + n0) * 128);
    const float4* c4  = (const float4*)(cmat + ((size_t)b * 256 + m0) * 128);
    const float4* b14 = (const float4*)bc1;
    for (int idx = tid; idx < 512; idx += 256) {
        int r = idx >> 5, q = idx & 31;
        float4 av = a4[r * 32 + q], bv = b14[q];
        a_s[r * 33 + q] = make_float4(av.x + bv.x, av.y + bv.y,
                                      av.z + bv.z, av.w + bv.w);
        c_s[r * 33 + q] = c4[r * 32 + q];
    }
    __syncthreads();

    const int ni = tid >> 4, mi = tid & 15;
    const float4* wp = (const float4*)wc2;
    float acc = bc2[0];
#pragma unroll 8
    for (int q = 0; q < 32; ++q) {
        float4 av = a_s[ni * 33 + q];
        float4 cv = c_s[mi * 33 + q];
        float4 wv = wp[q];                                    // uniform s_load
        acc = fmaf(fmaxf(av.x + cv.x, 0.f), wv.x, acc);
        acc = fmaf(fmaxf(av.y + cv.y, 0.f), wv.y, acc);
        acc = fmaf(fmaxf(av.z + cv.z, 0.f), wv.z, acc);
        acc = fmaf(fmaxf(av.w + cv.w, 0.f), wv.w, acc);
    }
    out[((size_t)b * 256 + n0 + ni) * 256 + m0 + mi] = acc;
}

extern "C" void kernel_launch(void* const* d_in, const int* in_sizes, int n_in,
                              void* d_out, int out_size, void* d_ws, size_t ws_size,
                              hipStream_t stream)
{
    const float* tracks = (const float*)d_in[0];
    const float* dets   = (const float*)d_in[1];
    const float* wa1 = (const float*)d_in[2];
    const float* ba1 = (const float*)d_in[3];
    const float* gla = (const float*)d_in[4];
    const float* bla = (const float*)d_in[5];
    const float* wa2 = (const float*)d_in[6];
    const float* ba2 = (const float*)d_in[7];
    const float* wg1 = (const float*)d_in[8];
    const float* bg1 = (const float*)d_in[9];
    const float* glg = (const float*)d_in[10];
    const float* blg = (const float*)d_in[11];
    const float* wg2 = (const float*)d_in[12];
    const float* bg2 = (const float*)d_in[13];
    const float* gf  = (const float*)d_in[14];
    const float* bf  = (const float*)d_in[15];
    // d_in[16..23]: attention weights — dead code in reference.
    const float* wc1 = (const float*)d_in[24];
    const float* bc1 = (const float*)d_in[25];
    const float* wc2 = (const float*)d_in[26];
    const float* bc2 = (const float*)d_in[27];
    float* out = (float*)d_out;
    float* ws  = (float*)d_ws;

    float* part = ws;
    float* aa   = ws + 4980736;
    float* cc   = ws + 5111808;

    hipLaunchKernelGGL(k_gemm1, dim3(512), dim3(256), 0, stream,
                       tracks, dets, wa1, part);
    hipLaunchKernelGGL(k_tail, dim3(512), dim3(256), 0, stream,
                       tracks, dets, part, ba1, gla, bla,
                       wg1, bg1, glg, blg, wa2, ba2, wg2, bg2,
                       gf, bf, wc1, aa, cc);
    hipLaunchKernelGGL(k_pairwise, dim3(1024), dim3(256), 0, stream,
                       aa, cc, bc1, wc2, bc2, out);
}